// Round 1
// baseline (115.931 us; speedup 1.0000x reference)
//
#include <hip/hip_runtime.h>

// SepConv on sphere, round 11: split coef prologue into a tiny precompute
// kernel (it depends only on h, but was recomputed 6x per row behind 3
// barriers with dependent scattered gathers on 144/512 threads). Main kernel
// now: issue 15 float4 x-loads -> coalesced 3.2KB C-row load from d_ws ->
// 1 barrier -> stencil FMA -> 1 barrier -> 32->64 GEMV.
//
// Algebra unchanged (absmax 0.0 since R2): the chain
//   x -> *qw -> DISCO(K=4,9tap) -> depth-mix -> *qw -> DISCO(K=1,4tap) -> 1x1
// composes into one 5x5 clip/wrap stencil with per-(c,h) coefs
// C[c][25] = w_depth[c,:] . S[4][25], then a 32->64 pointwise GEMV.
// coef_build uses the exact same summation order as the old in-block
// prologue, so results are bit-identical.

#define H_    181
#define W_    360
#define CIN_  32
#define COUT_ 64
#define K_    4
#define NNZ_  9
#define NNZ1_ 4
#define HW_   (H_*W_)
#define NT_   (NNZ1_*K_*NNZ_)   // 144 composed taps per output row
#define CSZ_  (CIN_*25)         // 800 floats per row of C

// ---------------------------------------------------------------------------
// Kernel 1: per-row composed coefficients C[h][c][25] -> workspace.
// 181 blocks x 256 threads; identical arithmetic/order to the old prologue.
// ---------------------------------------------------------------------------
__global__ __launch_bounds__(256) void coef_build(
    const float* __restrict__ quad_w, const float* __restrict__ vals,
    const int* __restrict__ hi, const int* __restrict__ wi,
    const float* __restrict__ w_depth, const float* __restrict__ vals1,
    const int* __restrict__ hi1, const int* __restrict__ wi1,
    float* __restrict__ Cg)
{
    const int h   = blockIdx.x;
    const int tid = threadIdx.x;

    __shared__ float Tval[NT_];
    __shared__ int   Tbin[NT_];
    __shared__ float S[K_][25];

    if (tid < NT_) {
        const int a   = tid / 36;
        const int rem = tid - a * 36;
        const int k   = rem / 9;
        const int j   = rem - k * 9;
        const int e1  = h * NNZ1_ + a;
        const int m   = hi1[e1];
        const int w1  = wi1[e1];
        const int d1  = (w1 == 1) ? 1 : ((w1 == 0) ? 0 : -1);
        const int e   = (k * H_ + m) * NNZ_ + j;
        const int r   = hi[e];
        const int ww  = wi[e];
        const int d   = (ww == 1) ? 1 : ((ww == 0) ? 0 : -1);
        Tval[tid] = vals1[e1] * quad_w[m] * vals[e] * quad_w[r];
        Tbin[tid] = (r - h + 2) * 5 + (d1 + d + 2);   // in [0,25)
    }
    __syncthreads();

    if (tid < K_ * 25) {       // deterministic scan, same order as before
        const int k   = tid / 25;
        const int bin = tid - k * 25;
        float s = 0.f;
        #pragma unroll
        for (int a = 0; a < NNZ1_; ++a)
            #pragma unroll
            for (int j = 0; j < NNZ_; ++j) {
                const int t2 = a * 36 + k * 9 + j;
                if (Tbin[t2] == bin) s += Tval[t2];
            }
        S[k][bin] = s;
    }
    __syncthreads();

    for (int i = tid; i < CSZ_; i += 256) {
        const int cc = i / 25, bin = i - cc * 25;
        float acc = 0.f;
        #pragma unroll
        for (int k = 0; k < K_; ++k) acc += w_depth[cc * K_ + k] * S[k][bin];
        Cg[h * CSZ_ + i] = acc;  // coalesced
    }
}

// ---------------------------------------------------------------------------
// Kernel 2: stencil + pointwise. 512 threads: (c = tid>>4, g = tid&15),
// one 4-px stencil item per thread, then (px j, o-eighth oh) GEMV.
// ---------------------------------------------------------------------------
__global__ __launch_bounds__(512) void sepconv_main(
    const float* __restrict__ x, const float* __restrict__ Cg,
    const float* __restrict__ w_point, const float* __restrict__ bias,
    float* __restrict__ out)
{
    const int bx = blockIdx.x;
    const int h  = (bx & 7) * 23 + (bx >> 3);   // XCD-contiguous row bands
    if (h >= H_) return;                         // 3 pad rows, uniform exit
    const int seg = blockIdx.y;                  // 0..5
    const int w0  = seg * 64;
    const int pxn = (seg == 5) ? 40 : 64;        // 360 = 5*64 + 40
    const int gn  = pxn >> 2;
    const int tid = threadIdx.x;

    __shared__ __attribute__((aligned(16))) float C[CIN_][25];
    __shared__ float zs[64][33];   // [px][ch]; <=2-way banks everywhere (free)

    // --- x prefetch FIRST: latency drains behind the C-row load -------------
    const int g = tid & 15;
    const int c = tid >> 4;
    const bool act = (g < gn);

    int rowoff[5];
    #pragma unroll
    for (int rb = 0; rb < 5; ++rb) {
        int r = h - 2 + rb;
        r = (r < 0) ? 0 : ((r > H_ - 1) ? H_ - 1 : r);
        rowoff[rb] = r * W_;
    }

    const int bw = w0 + g * 4;
    const int cA = (bw + W_ - 4) % W_;
    const int cB = bw;
    const int cC = (bw + 4) % W_;

    float4 L[15];
    if (act) {
        const float* xc = x + c * HW_;
        #pragma unroll
        for (int rb = 0; rb < 5; ++rb) {
            const float* xr = xc + rowoff[rb];
            L[rb * 3 + 0] = *(const float4*)(xr + cA);   // in flight during
            L[rb * 3 + 1] = *(const float4*)(xr + cB);   // the C load below
            L[rb * 3 + 2] = *(const float4*)(xr + cC);
        }
    }

    // --- C-row load: one coalesced float2 per thread (400 threads) ----------
    if (tid < CSZ_ / 2)
        ((float2*)&C[0][0])[tid] =
            ((const float2*)(Cg + h * CSZ_))[tid];
    __syncthreads();

    // --- Phase A: FMA on prefetched registers -> LDS z tile -----------------
    if (act) {
        const float* Cc = &C[c][0];
        float a0 = 0.f, a1 = 0.f, a2 = 0.f, a3 = 0.f;
        #pragma unroll
        for (int rb = 0; rb < 5; ++rb) {
            const float4 vA = L[rb * 3 + 0];
            const float4 vB = L[rb * 3 + 1];
            const float4 vC = L[rb * 3 + 2];
            const float k0 = Cc[rb * 5 + 0], k1 = Cc[rb * 5 + 1],
                        k2 = Cc[rb * 5 + 2], k3 = Cc[rb * 5 + 3],
                        k4 = Cc[rb * 5 + 4];
            a0 += k0 * vA.z + k1 * vA.w + k2 * vB.x + k3 * vB.y + k4 * vB.z;
            a1 += k0 * vA.w + k1 * vB.x + k2 * vB.y + k3 * vB.z + k4 * vB.w;
            a2 += k0 * vB.x + k1 * vB.y + k2 * vB.z + k3 * vB.w + k4 * vC.x;
            a3 += k0 * vB.y + k1 * vB.z + k2 * vB.w + k3 * vC.x + k4 * vC.y;
        }
        const int p = g * 4;
        zs[p + 0][c] = a0;      // bank (4g+u+c)%32: each hit 2x -> free
        zs[p + 1][c] = a1;
        zs[p + 2][c] = a2;
        zs[p + 3][c] = a3;
    }
    __syncthreads();

    // --- Phase B: 32->64 GEMV; thread = (px j, o-eighth oh) -----------------
    const int j  = tid & 63;
    const int oh = tid >> 6;            // 0..7, wave-uniform
    if (j < pxn) {
        float zr[CIN_];
        #pragma unroll
        for (int cc = 0; cc < CIN_; ++cc) zr[cc] = zs[j][cc];   // 2-way, free

        const float* wp = w_point + oh * 8 * CIN_;              // s_loads
        float* op = out + oh * 8 * HW_ + h * W_ + w0 + j;
        #pragma unroll
        for (int oo = 0; oo < 8; ++oo) {
            float acc = bias[oh * 8 + oo];
            #pragma unroll
            for (int cc = 0; cc < CIN_; ++cc)
                acc += wp[oo * CIN_ + cc] * zr[cc];
            op[oo * HW_] = acc;          // 256B contiguous per wave
        }
    }
}

extern "C" void kernel_launch(void* const* d_in, const int* in_sizes, int n_in,
                              void* d_out, int out_size, void* d_ws, size_t ws_size,
                              hipStream_t stream) {
    const float* x       = (const float*)d_in[0];
    const float* quad_w  = (const float*)d_in[1];
    const float* vals    = (const float*)d_in[2];
    // d_in[3] = seg  (unused; tap membership implied by entry ordering)
    const int*   hi      = (const int*)d_in[4];
    const int*   wi      = (const int*)d_in[5];
    const float* w_depth = (const float*)d_in[6];
    const float* vals1   = (const float*)d_in[7];
    // d_in[8] = seg1 (unused)
    const int*   hi1     = (const int*)d_in[9];
    const int*   wi1     = (const int*)d_in[10];
    const float* w_point = (const float*)d_in[11];
    const float* bias    = (const float*)d_in[12];
    // d_in[13] = K (compile-time constant 4)

    float* Cg = (float*)d_ws;   // 181*800*4 B = 579 KB << ws_size

    coef_build<<<dim3(181), 256, 0, stream>>>(
        quad_w, vals, hi, wi, w_depth, vals1, hi1, wi1, Cg);
    sepconv_main<<<dim3(184, 6), 512, 0, stream>>>(
        x, Cg, w_point, bias, (float*)d_out);
}

// Round 2
// 114.013 us; speedup vs baseline: 1.0168x; 1.0168x over previous
//
#include <hip/hip_runtime.h>

// SepConv on sphere, round 12: de-fuse into three barrier-free streaming
// kernels. R11 proved the coef prologue was not the cost; the remaining
// ~28us of kernel time is latency-bound structure: 512-thr blocks at ~2
// blocks/CU with two LDS phase barriers. Replace with:
//   1) coef_build  -> Cg[h][c][32] (padded, float4-loadable)  [181 blocks]
//   2) stencil_z   -> z[32][181][360] in ws; 1 thread per (c,h,4px), no LDS,
//                     no barriers, XCD-bijective block remap      [2037 blocks]
//   3) pointwise   -> 32->64 GEMV per px, wave-uniform s_loaded w_point,
//                     ~50 VGPR, 32 waves/CU                       [510 blocks]
// All FP summation orders identical to the verified fused path (absmax 0.0).

#define H_    181
#define W_    360
#define CIN_  32
#define COUT_ 64
#define K_    4
#define NNZ_  9
#define NNZ1_ 4
#define HW_   (H_*W_)
#define NT_   (NNZ1_*K_*NNZ_)   // 144 composed taps per output row
#define CROW_ 32                // padded floats per (h,c) coef row (16B align)
#define CSZH_ (CIN_*CROW_)      // 1024 floats per h
#define ZOFF_ ((size_t)1 << 20) // z offset in workspace (Cg uses 741KB)

// ---------------------------------------------------------------------------
// Kernel 1: per-row composed coefficients C[h][c][25] -> ws (padded rows).
// Identical arithmetic/order to the verified in-block prologue.
// ---------------------------------------------------------------------------
__global__ __launch_bounds__(256) void coef_build(
    const float* __restrict__ quad_w, const float* __restrict__ vals,
    const int* __restrict__ hi, const int* __restrict__ wi,
    const float* __restrict__ w_depth, const float* __restrict__ vals1,
    const int* __restrict__ hi1, const int* __restrict__ wi1,
    float* __restrict__ Cg)
{
    const int h   = blockIdx.x;
    const int tid = threadIdx.x;

    __shared__ float Tval[NT_];
    __shared__ int   Tbin[NT_];
    __shared__ float S[K_][25];

    if (tid < NT_) {
        const int a   = tid / 36;
        const int rem = tid - a * 36;
        const int k   = rem / 9;
        const int j   = rem - k * 9;
        const int e1  = h * NNZ1_ + a;
        const int m   = hi1[e1];
        const int w1  = wi1[e1];
        const int d1  = (w1 == 1) ? 1 : ((w1 == 0) ? 0 : -1);
        const int e   = (k * H_ + m) * NNZ_ + j;
        const int r   = hi[e];
        const int ww  = wi[e];
        const int d   = (ww == 1) ? 1 : ((ww == 0) ? 0 : -1);
        Tval[tid] = vals1[e1] * quad_w[m] * vals[e] * quad_w[r];
        Tbin[tid] = (r - h + 2) * 5 + (d1 + d + 2);   // in [0,25)
    }
    __syncthreads();

    if (tid < K_ * 25) {       // deterministic scan, same order as before
        const int k   = tid / 25;
        const int bin = tid - k * 25;
        float s = 0.f;
        #pragma unroll
        for (int a = 0; a < NNZ1_; ++a)
            #pragma unroll
            for (int j = 0; j < NNZ_; ++j) {
                const int t2 = a * 36 + k * 9 + j;
                if (Tbin[t2] == bin) s += Tval[t2];
            }
        S[k][bin] = s;
    }
    __syncthreads();

    for (int i = tid; i < CIN_ * 25; i += 256) {
        const int cc = i / 25, bin = i - cc * 25;
        float acc = 0.f;
        #pragma unroll
        for (int k = 0; k < K_; ++k) acc += w_depth[cc * K_ + k] * S[k][bin];
        Cg[h * CSZH_ + cc * CROW_ + bin] = acc;
    }
}

// ---------------------------------------------------------------------------
// Kernel 2: 25-tap stencil -> z[c][h][w] in ws. One thread per (c,h,4px).
// No LDS, no barriers; 22 loads issued up front, one waitcnt, 100 FMA, store.
// ---------------------------------------------------------------------------
__global__ __launch_bounds__(256) void stencil_z(
    const float* __restrict__ x, const float* __restrict__ Cg,
    float* __restrict__ z)
{
    // bijective XCD-contiguous remap (m204): each XCD gets a contiguous
    // (c,h) span so adjacent-h blocks share x rows in the same L2.
    const int nwg  = (int)gridDim.x;
    const int orig = (int)blockIdx.x;
    const int q = nwg >> 3, r = nwg & 7;
    const int xcd = orig & 7, off = orig >> 3;
    const int wg  = (xcd < r ? xcd * (q + 1)
                             : r * (q + 1) + (xcd - r) * q) + off;

    const int lin = wg * 256 + (int)threadIdx.x;
    if (lin >= CIN_ * H_ * 90) return;
    const int c   = lin / (H_ * 90);
    const int rem = lin - c * (H_ * 90);
    const int h   = rem / 90;
    const int g   = rem - h * 90;

    int rowoff[5];
    #pragma unroll
    for (int rb = 0; rb < 5; ++rb) {
        int rr = h - 2 + rb;
        rr = (rr < 0) ? 0 : ((rr > H_ - 1) ? H_ - 1 : rr);
        rowoff[rb] = rr * W_;
    }
    const int bw = g * 4;
    const int cA = (bw + W_ - 4) % W_;
    const int cB = bw;
    const int cC = (bw + 4) % W_;

    const float* xc = x + c * HW_;
    float4 L[15];
    #pragma unroll
    for (int rb = 0; rb < 5; ++rb) {
        const float* xr = xc + rowoff[rb];
        L[rb * 3 + 0] = *(const float4*)(xr + cA);
        L[rb * 3 + 1] = *(const float4*)(xr + cB);
        L[rb * 3 + 2] = *(const float4*)(xr + cC);
    }

    // coef row: 7 float4 (k[25..27] are pad, never consumed)
    const float* Cc = Cg + h * CSZH_ + c * CROW_;
    float k[28];
    #pragma unroll
    for (int i = 0; i < 7; ++i)
        ((float4*)k)[i] = ((const float4*)Cc)[i];

    float a0 = 0.f, a1 = 0.f, a2 = 0.f, a3 = 0.f;
    #pragma unroll
    for (int rb = 0; rb < 5; ++rb) {
        const float4 vA = L[rb * 3 + 0];
        const float4 vB = L[rb * 3 + 1];
        const float4 vC = L[rb * 3 + 2];
        const float k0 = k[rb * 5 + 0], k1 = k[rb * 5 + 1],
                    k2 = k[rb * 5 + 2], k3 = k[rb * 5 + 3],
                    k4 = k[rb * 5 + 4];
        a0 += k0 * vA.z + k1 * vA.w + k2 * vB.x + k3 * vB.y + k4 * vB.z;
        a1 += k0 * vA.w + k1 * vB.x + k2 * vB.y + k3 * vB.z + k4 * vB.w;
        a2 += k0 * vB.x + k1 * vB.y + k2 * vB.z + k3 * vB.w + k4 * vC.x;
        a3 += k0 * vB.y + k1 * vB.z + k2 * vB.w + k3 * vC.x + k4 * vC.y;
    }
    *(float4*)(z + c * HW_ + h * W_ + bw) = make_float4(a0, a1, a2, a3);
}

// ---------------------------------------------------------------------------
// Kernel 3: 32->64 pointwise GEMV per pixel. thread = (px, o-quarter).
// w_point rows are wave-uniform (readfirstlane) -> s_loads; z loads and out
// stores fully coalesced. ~50 VGPR -> 32 waves/CU.
// ---------------------------------------------------------------------------
__global__ __launch_bounds__(512) void pointwise(
    const float* __restrict__ z, const float* __restrict__ w_point,
    const float* __restrict__ bias, float* __restrict__ out)
{
    const int tid = (int)threadIdx.x;
    const int oq  = __builtin_amdgcn_readfirstlane(tid >> 7);   // 0..3, uniform
    const int p   = tid & 127;
    const int px  = (int)blockIdx.x * 128 + p;
    if (px >= HW_) return;

    float zr[CIN_];
    #pragma unroll
    for (int cc = 0; cc < CIN_; ++cc) zr[cc] = z[cc * HW_ + px];

    const float* wp = w_point + oq * 16 * CIN_;
    const float* bq = bias + oq * 16;
    float* op = out + oq * 16 * HW_ + px;
    #pragma unroll 4
    for (int o = 0; o < 16; ++o) {
        float acc = bq[o];
        #pragma unroll
        for (int cc = 0; cc < CIN_; ++cc)
            acc += wp[o * CIN_ + cc] * zr[cc];
        op[o * HW_] = acc;        // 512B contiguous per wave
    }
}

extern "C" void kernel_launch(void* const* d_in, const int* in_sizes, int n_in,
                              void* d_out, int out_size, void* d_ws, size_t ws_size,
                              hipStream_t stream) {
    const float* x       = (const float*)d_in[0];
    const float* quad_w  = (const float*)d_in[1];
    const float* vals    = (const float*)d_in[2];
    // d_in[3] = seg  (unused; tap membership implied by entry ordering)
    const int*   hi      = (const int*)d_in[4];
    const int*   wi      = (const int*)d_in[5];
    const float* w_depth = (const float*)d_in[6];
    const float* vals1   = (const float*)d_in[7];
    // d_in[8] = seg1 (unused)
    const int*   hi1     = (const int*)d_in[9];
    const int*   wi1     = (const int*)d_in[10];
    const float* w_point = (const float*)d_in[11];
    const float* bias    = (const float*)d_in[12];
    // d_in[13] = K (compile-time constant 4)

    float* Cg = (float*)d_ws;                       // 181*1024*4 = 741 KB
    float* z  = (float*)((char*)d_ws + ZOFF_);      // 32*181*360*4 = 8.3 MB

    coef_build<<<dim3(181), 256, 0, stream>>>(
        quad_w, vals, hi, wi, w_depth, vals1, hi1, wi1, Cg);
    stencil_z<<<dim3((CIN_ * H_ * 90 + 255) / 256), 256, 0, stream>>>(
        x, Cg, z);
    pointwise<<<dim3((HW_ + 127) / 128), 512, 0, stream>>>(
        z, w_point, bias, (float*)d_out);
}